// Round 5
// baseline (196.997 us; speedup 1.0000x reference)
//
#include <hip/hip_runtime.h>
#include <stdint.h>

// Problem constants
#define BATCH 32
#define LLEN  36864
#define CCH   16
#define DOUT  512
#define KW    24
#define LOUT  1536            // LLEN / KW
#define MROWS (BATCH * LOUT)  // 49152 windows
#define CK    384             // CCH * KW (inner dot length)
#define TWOK  48

typedef float fx4 __attribute__((ext_vector_type(4)));
typedef float f32x4 __attribute__((ext_vector_type(4)));
typedef __bf16 bf16x8 __attribute__((ext_vector_type(8)));
typedef __bf16 bf16x4 __attribute__((ext_vector_type(4)));
typedef uint32_t u32x4 __attribute__((ext_vector_type(4)));

#define VMCNT(n)  asm volatile("s_waitcnt vmcnt(" #n ")" ::: "memory")
#define LGKMCNT0  asm volatile("s_waitcnt lgkmcnt(0)" ::: "memory")
#define SCHEDB    __builtin_amdgcn_sched_barrier(0)
#define SBAR      __builtin_amdgcn_s_barrier()

__device__ __forceinline__ void gload16(void* lds, const void* g)
{
    __builtin_amdgcn_global_load_lds(
        (const __attribute__((address_space(1))) uint32_t*)g,
        (__attribute__((address_space(3))) uint32_t*)lds, 16, 0, 0);
}

// ---------------------------------------------------------------------------
// K0: weight transposition to j = k*16+c layout (bf16).
// ---------------------------------------------------------------------------
__global__ __launch_bounds__(256) void prep_kernel(
    const float* __restrict__ w_off, const float* __restrict__ w_def,
    __bf16* __restrict__ woff_b, __bf16* __restrict__ wdef_b)
{
    int idx = blockIdx.x * 256 + threadIdx.x;
    if (idx < TWOK * CK) {
        int o = idx / CK, rem = idx % CK;
        int k = rem >> 4, c = rem & 15;
        woff_b[idx] = (__bf16)w_off[o * CK + c * KW + k];
    }
    if (idx < DOUT * CK) {
        int d = idx / CK, rem = idx % CK;
        int k = rem >> 4, c = rem & 15;
        wdef_b[idx] = (__bf16)w_def[d * CK + c * KW + k];
    }
}

// ---------------------------------------------------------------------------
// K1: fused offsets + gather + GEMM.
// R3 post-mortem: counted-vmcnt pipeline == R0 full-drain (78 us both) =>
// bottleneck is a shared resource: L1 request rate.  Old gather: each
// global_load_dwordx4 had 64 lanes on 64 DISTINCT 64B lines (no intra-
// instruction coalescing) -> ~6k L1 tag-lookups/CU-iter just for gathers.
// R5: cooperative transposed gather -- the 4 lanes of a quad (same row)
// read the SAME line: thread (row,j4) loads 16B chunk j4 of the row's 8
// needed lines (4 k-slots x {i0,i1}).  Same instr count/bytes, 4x fewer
// distinct lines per instruction.  (dy,dx) redistributed in-quad via
// ds_swizzle quad-broadcast (BitMode and=0x1C, or=idx -> literal patterns
// 0x1C/0x3C/0x5C/0x7C; builtin requires literal imm).  Pack = 4 x
// (fma+cvt+ds_write_b64) into the same XOR-swizzled As layout.
// vmcnt schedule identical to R3 (G:8, D:4 per wave).
// ---------------------------------------------------------------------------
#define BM 96
#define BN 512
#define BK 64   // per-cc gather granularity; DMA/MFMA phases are BK/2=32

__global__ __launch_bounds__(512) void gemm_fused(
    const float* __restrict__ x, const __bf16* __restrict__ woff_b,
    const float* __restrict__ b_off, const __bf16* __restrict__ Bw,
    const float* __restrict__ bias, float* __restrict__ out)
{
    __shared__ char smem[77824];
    __bf16* As  = (__bf16*)smem;                 // [96][64]  = 12288 B
    __bf16* Bs0 = (__bf16*)(smem + 12288);       // [512][32] = 32768 B
    __bf16* Bs1 = (__bf16*)(smem + 45056);       // [512][32] = 32768 B
    __bf16* WoffS = (__bf16*)smem;               // [48][392] prologue, 37632 B
    float*  offS  = (float*)(smem + 45056);      // [96][49]  prologue, 18816 B
                                                 // (inside Bs1; D(1) issues
                                                 //  only after dxyr packed)

    const int t = threadIdx.x;
    const int m0 = blockIdx.x * BM;
    const int wave = t >> 6, lane = t & 63;
    const int quad = lane >> 4, l16 = lane & 15;
    const int wr = wave >> 2, wc = wave & 3;        // 2x4 waves: tile 48x128

    // gather ownership (threads 0..383): row mloc, chunk j4 (16B of a line)
    const int mloc = t >> 2, j4 = t & 3;
    const int Mrow = m0 + mloc;
    const int b    = m0 / LOUT;                     // 1536 % 96 == 0
    const int lb   = Mrow - b * LOUT;
    const float* xb = x + (size_t)b * LLEN * CCH;

    // ---- prologue: stage woff ----
#pragma unroll
    for (int i = 0; i < 5; ++i) {
        int q = t + 512 * i;                        // 2304 16B chunks
        if (q < 2304) {
            int row = q / 48, cc = q - row * 48;
            *(u32x4*)&WoffS[row * 392 + cc * 8] =
                *(const u32x4*)&woff_b[row * CK + cc * 8];
        }
    }
    __syncthreads();

    // ---- prologue: offsets MFMA (waves 0..5 cover 96 rows) ----
    if (wave < 6) {
        const float* xr = x + (size_t)(m0 + wave * 16 + l16) * CK;
        f32x4 oacc[3] = {};
#pragma unroll
        for (int ks = 0; ks < 12; ++ks) {
            int k0 = ks * 32 + quad * 8;
            fx4 a0 = *(const fx4*)&xr[k0];
            fx4 a1 = *(const fx4*)&xr[k0 + 4];
            bf16x8 af;
            af[0] = (__bf16)a0.x; af[1] = (__bf16)a0.y;
            af[2] = (__bf16)a0.z; af[3] = (__bf16)a0.w;
            af[4] = (__bf16)a1.x; af[5] = (__bf16)a1.y;
            af[6] = (__bf16)a1.z; af[7] = (__bf16)a1.w;
#pragma unroll
            for (int j = 0; j < 3; ++j) {
                bf16x8 bf = *(const bf16x8*)&WoffS[(j * 16 + l16) * 392 + k0];
                oacc[j] = __builtin_amdgcn_mfma_f32_16x16x32_bf16(af, bf, oacc[j], 0, 0, 0);
            }
        }
        float bo[3];
#pragma unroll
        for (int j = 0; j < 3; ++j) bo[j] = b_off[j * 16 + l16];
#pragma unroll
        for (int j = 0; j < 3; ++j)
#pragma unroll
            for (int r = 0; r < 4; ++r)
                offS[(wave * 16 + quad * 4 + r) * 49 + j * 16 + l16] = oacc[j][r] + bo[j];
    }
    __syncthreads();

    // ---- prologue: pack this thread's 6 (dy,dx) pairs into regs ----
    uint32_t dxyr[6];
    if (t < 4 * BM) {
#pragma unroll
        for (int cc = 0; cc < 6; ++cc) {
            int kk = 4 * cc + j4;
            float dy = offS[mloc * 49 + 2 * kk];
            float dx = offS[mloc * 49 + 2 * kk + 1];
            union { __bf16 h[2]; uint32_t u; } p;
            p.h[0] = (__bf16)dy; p.h[1] = (__bf16)dx;
            dxyr[cc] = p.u;
        }
    }

    f32x4 acc[3][8] = {};
    fx4 L[8];                 // 8 x 16B chunks: 4 k-slots x {i0,i1}
    float wA[4], wB[4];       // weights per k-slot

    // Cooperative gather issue: redistribute the quad's 4 (dy,dx) pairs via
    // ds_swizzle quad-broadcast (literal BitMode patterns), then each lane
    // loads chunk j4 of all 8 lines.  4 lanes of a quad hit the SAME line
    // per load -> 16 distinct lines per wave-instruction instead of 64.
    auto gather_issue = [&](int cc, int kbase) {
        uint32_t pk[4];
        pk[0] = __builtin_amdgcn_ds_swizzle(dxyr[cc], 0x001C);  // lane base+0
        pk[1] = __builtin_amdgcn_ds_swizzle(dxyr[cc], 0x003C);  // lane base+1
        pk[2] = __builtin_amdgcn_ds_swizzle(dxyr[cc], 0x005C);  // lane base+2
        pk[3] = __builtin_amdgcn_ds_swizzle(dxyr[cc], 0x007C);  // lane base+3
#pragma unroll
        for (int kk = 0; kk < 4; ++kk) {
            union { uint32_t u; __bf16 h[2]; } p; p.u = pk[kk];
            float dy = (float)p.h[0], dx = (float)p.h[1];
            float wy  = fmaxf(0.f, 1.f - fabsf(dy));
            float px  = (float)(lb * KW + kbase + kk) + dx;
            float x0f = floorf(px);
            float lw  = px - x0f;
            int   i0  = (int)x0f;
            bool valid = (px > -1.0f) && (px < (float)LLEN);
            wA[kk] = (valid && i0 >= 0)         ? (1.f - lw) * wy : 0.f;
            wB[kk] = (valid && (i0 + 1) < LLEN) ? lw * wy         : 0.f;
            int i0c = min(max(i0, 0), LLEN - 1);
            int i1c = min(max(i0 + 1, 0), LLEN - 1);
            L[2 * kk]     = *(const fx4*)&xb[(size_t)i0c * CCH + 4 * j4];
            L[2 * kk + 1] = *(const fx4*)&xb[(size_t)i1c * CCH + 4 * j4];
        }
    };

    // Pack: thread (mloc, j4) owns channels 4*j4..4*j4+3 of 4 k-slots.
    // As element index within row = kk*16 + c; 16B-chunk g = kk*2 + (j4>>1),
    // XOR-swizzled by row as before; b64 write at half-chunk (j4&1).
    auto pack_write = [&]() {
#pragma unroll
        for (int kk = 0; kk < 4; ++kk) {
            fx4 v;
            v.x = wA[kk] * L[2 * kk].x + wB[kk] * L[2 * kk + 1].x;
            v.y = wA[kk] * L[2 * kk].y + wB[kk] * L[2 * kk + 1].y;
            v.z = wA[kk] * L[2 * kk].z + wB[kk] * L[2 * kk + 1].z;
            v.w = wA[kk] * L[2 * kk].w + wB[kk] * L[2 * kk + 1].w;
            bf16x4 h;
            h[0] = (__bf16)v.x; h[1] = (__bf16)v.y;
            h[2] = (__bf16)v.z; h[3] = (__bf16)v.w;
            int g = kk * 2 + (j4 >> 1);
            int idx = mloc * BK + ((g ^ (mloc & 7)) * 8) + (j4 & 1) * 4;
            *(bf16x4*)&As[idx] = h;
        }
    };

    // DMA one BK=32 phase (32 KB) into buf: 2048 chunks / 512 thr = 4 each.
    // LDS dest linear in chunk index; source carries the XOR swizzle slot
    // s^((c>>1)&3) so ds_read is conflict-free.
    auto dma_phase = [&](int ph, __bf16* buf) {
#pragma unroll
        for (int it = 0; it < 4; ++it) {
            int q = it * 512 + t;
            int c = q >> 2, s = q & 3;
            int ss = s ^ ((c >> 1) & 3);
            gload16(&buf[q * 8], Bw + (size_t)c * CK + ph * 32 + ss * 8);
        }
    };

    auto mfma_phase = [&](int ks, const __bf16* Bsb) {
        bf16x8 af[3], bfr[8];
#pragma unroll
        for (int i = 0; i < 3; ++i) {
            int row = wr * 48 + i * 16 + l16;
            af[i] = *(const bf16x8*)&As[row * BK + (((ks * 4 + quad) ^ (row & 7)) * 8)];
        }
#pragma unroll
        for (int j = 0; j < 8; ++j) {
            int col = wc * 128 + j * 16 + l16;
            bfr[j] = *(const bf16x8*)&Bsb[col * 32 + ((quad ^ ((col >> 1) & 3)) * 8)];
        }
#pragma unroll
        for (int i = 0; i < 3; ++i)
#pragma unroll
            for (int j = 0; j < 8; ++j)
                acc[i][j] = __builtin_amdgcn_mfma_f32_16x16x32_bf16(
                    af[i], bfr[j], acc[i][j], 0, 0, 0);
    };

    // ---- prologue issues: G(0) then D(0) (queue order matters) ----
    if (t < 4 * BM) gather_issue(0, 0);         // G(0): 8 loads
    SCHEDB;
    dma_phase(0, Bs0);                          // D(0): 4 loads
    SCHEDB;

#pragma unroll
    for (int cc = 0; cc < 6; ++cc) {
        SBAR;                                   // Z: As free (prev readers done)
        SCHEDB;
        VMCNT(4);                               // G(cc) done (trivial for w6,7)
        SCHEDB;
        if (t < 4 * BM) pack_write();           // As from gathered regs
        SCHEDB;
        dma_phase(2 * cc + 1, Bs1);             // D(2cc+1) BEFORE G(cc+1)!
        SCHEDB;
        if (cc + 1 < 6 && t < 4 * BM)
            gather_issue(cc + 1, 4 * (cc + 1)); // G(cc+1): 8 loads
        SCHEDB;
        LGKMCNT0;                               // own As ds_writes done
        SCHEDB;
        SBAR;                                   // A: As visible to all
        SCHEDB;
        // wait own D(2cc): gather queue {D4,D4,G8} -> <=12; w6,7 -> <=4
        if (cc < 5) { if (wave < 6) { VMCNT(12); } else { VMCNT(4); } }
        else        { VMCNT(4); }               // cc=5: no G in queue
        SCHEDB;
        SBAR;                                   // C0: Bs0 ready (all waves)
        SCHEDB;
        __builtin_amdgcn_s_setprio(1);
        mfma_phase(0, Bs0);
        __builtin_amdgcn_s_setprio(0);
        SCHEDB;
        // wait own D(2cc+1): gather {D4,G8} -> <=8; w6,7 -> 0
        if (cc < 5) { if (wave < 6) { VMCNT(8); } else { VMCNT(0); } }
        else        { VMCNT(0); }
        SCHEDB;
        SBAR;                                   // BC1: Bs1 ready; Bs0 free
        SCHEDB;
        if (cc < 5) dma_phase(2 * cc + 2, Bs0); // D(2cc+2), flies under MFMA
        SCHEDB;
        __builtin_amdgcn_s_setprio(1);
        mfma_phase(1, Bs1);
        __builtin_amdgcn_s_setprio(0);
        SCHEDB;
    }

    // epilogue: D[row=quad*4+r][col=l16]
#pragma unroll
    for (int j = 0; j < 8; ++j) {
        int col = wc * 128 + j * 16 + l16;
        float bj = bias[col];
#pragma unroll
        for (int i = 0; i < 3; ++i) {
            int rowb = m0 + wr * 48 + i * 16 + quad * 4;
#pragma unroll
            for (int r = 0; r < 4; ++r)
                out[(size_t)(rowb + r) * DOUT + col] = acc[i][j][r] + bj;
        }
    }
}

// ---------------------------------------------------------------------------
extern "C" void kernel_launch(void* const* d_in, const int* in_sizes, int n_in,
                              void* d_out, int out_size, void* d_ws, size_t ws_size,
                              hipStream_t stream)
{
    const float* x     = (const float*)d_in[0];
    const float* w_off = (const float*)d_in[1];
    const float* b_off = (const float*)d_in[2];
    const float* w_def = (const float*)d_in[3];
    const float* b_def = (const float*)d_in[4];
    float* out = (float*)d_out;

    char* ws = (char*)d_ws;
    __bf16* wdef_b = (__bf16*)ws;                 // 393,216 B
    __bf16* woff_b = (__bf16*)(ws + 393216);      //  36,864 B

    prep_kernel<<<768, 256, 0, stream>>>(w_off, w_def, woff_b, wdef_b);
    gemm_fused<<<MROWS / BM, 512, 0, stream>>>(x, woff_b, b_off, wdef_b, b_def, out);
}